// Round 2
// baseline (985.130 us; speedup 1.0000x reference)
//
#include <hip/hip_runtime.h>

// ---------------------------------------------------------------------------
// RNN_83313775608289: 4-layer tanh RNN (H=64) + FC, B=512, T=1024, D_in=52.
// Structure:
//   kernel 1 (pre0_kernel): pre0 = x @ Wih0^T + (bih0+bhh0), stored as packed
//                           f16 pairs in d_ws (64 MiB). Parallel, ~mem-bound.
//   kernel 2 (rnn_pipe):    one block per batch row; 4 waves = 4 layers in a
//                           software pipeline (wave l at t = s-l), h handed
//                           wave->wave via LDS (packed f16 pairs). FC fused
//                           into wave 0 (consumes h3 from LDS, 4-step skew).
//                           Matvecs: v_readlane broadcast + v_dot2_f32_f16,
//                           weights held as 32 f16-pair VGPRs per matrix.
// ---------------------------------------------------------------------------

typedef __fp16 h2 __attribute__((ext_vector_type(2)));  // matches builtin type

__device__ __forceinline__ h2 pk2(float a, float b) {
#if __has_builtin(__builtin_amdgcn_cvt_pkrtz)
  return __builtin_amdgcn_cvt_pkrtz(a, b);
#else
  h2 r; r.x = (__fp16)a; r.y = (__fp16)b; return r;
#endif
}

__device__ __forceinline__ float fdot2f(h2 a, h2 b, float c) {
#if __has_builtin(__builtin_amdgcn_fdot2)
  return __builtin_amdgcn_fdot2(a, b, c, false);
#else
  return c + (float)a.x * (float)b.x + (float)a.y * (float)b.y;
#endif
}

// broadcast the packed f16 pair held by `srclane` to all lanes
__device__ __forceinline__ h2 bcast_pair(int packed, int srclane) {
  return __builtin_bit_cast(h2, __builtin_amdgcn_readlane(packed, srclane));
}

__device__ __forceinline__ float fast_tanh(float x) {
  float e = __expf(2.0f * x);          // overflow -> +inf -> result 1.0 (ok)
#if __has_builtin(__builtin_amdgcn_rcpf)
  return 1.0f - 2.0f * __builtin_amdgcn_rcpf(e + 1.0f);
#else
  return 1.0f - 2.0f / (e + 1.0f);
#endif
}

// lane j holds h_j; produce (on even lanes) the pair (h_{2k}, h_{2k+1}) so
// readlane(hp, 2*k) broadcasts pair k. Odd-lane content is unused.
__device__ __forceinline__ int pack_own(float h, int lane) {
  float o = __shfl_xor(h, 1);
  h2 p = (lane & 1) ? pk2(o, h) : pk2(h, o);
  return __builtin_bit_cast(int, p);
}

#define T_STEPS 1024

// ---------------------------------------------------------------------------
// Kernel 1: pre0[r][j] = sum_d x[r][d] * Wih0[j][d] + bih0[j] + bhh0[j]
// r = b*T + t (rows of x, 52 floats each). Output packed f16 pairs [r][32].
// One row per wave, grid-stride; Wih0 row j lives in 26 f16-pair VGPRs.
// ---------------------------------------------------------------------------
__global__ __launch_bounds__(256) void pre0_kernel(
    const float* __restrict__ x, const float* __restrict__ Wih0,
    const float* __restrict__ bih0, const float* __restrict__ bhh0,
    unsigned int* __restrict__ pre0h, int R) {
  const int lane = threadIdx.x & 63;
  const int wv   = threadIdx.x >> 6;
  const int gw   = blockIdx.x * 4 + wv;
  const int NW   = gridDim.x * 4;

  h2 w[26];
#pragma unroll
  for (int k = 0; k < 26; ++k)
    w[k] = pk2(Wih0[lane * 52 + 2 * k], Wih0[lane * 52 + 2 * k + 1]);
  const float bias = bih0[lane] + bhh0[lane];

  const float2* x2 = (const float2*)x;  // 52 floats = 26 float2 per row
  for (int r = gw; r < R; r += NW) {
    float2 xv = make_float2(0.f, 0.f);
    if (lane < 26) xv = x2[(long)r * 26 + lane];
    int xp = __builtin_bit_cast(int, pk2(xv.x, xv.y));  // pair d at lane d
    float a0 = bias, a1 = 0.f;
#pragma unroll
    for (int k = 0; k < 26; k += 2) {
      a0 = fdot2f(bcast_pair(xp, k),     w[k],     a0);
      a1 = fdot2f(bcast_pair(xp, k + 1), w[k + 1], a1);
    }
    float acc = a0 + a1;
    float o   = __shfl_xor(acc, 1);
    if (!(lane & 1))
      pre0h[(long)r * 32 + (lane >> 1)] =
          __builtin_bit_cast(unsigned int, pk2(acc, o));
  }
}

// ---------------------------------------------------------------------------
// Kernel 2: pipelined 4-layer scan + fused FC. One block (4 waves) per row b.
//   wave 0: layer-0 recurrence (input from pre0h) at t=s, AND the FC stage
//           consuming h3 (from LDS) at t=s-4.
//   wave l (1..3): h^l_t = tanh(Wih_l h^{l-1}_t + b + Whh_l h^l_{t-1}), t=s-l.
// LDS handoff: hbuf[l][s&1][pair], packed f16 pairs, written by even lanes.
// One uniform __syncthreads per step (no divergent barriers).
// ---------------------------------------------------------------------------
__global__ __launch_bounds__(256, 2) void rnn_pipe(
    const unsigned int* __restrict__ pre0h, const float* __restrict__ Whh0,
    const float* __restrict__ Wih, const float* __restrict__ Whh,
    const float* __restrict__ bih, const float* __restrict__ bhh,
    const float* __restrict__ Wfc, const float* __restrict__ bfc,
    float* __restrict__ out) {
  const int lane = threadIdx.x & 63;
  const int wv   = threadIdx.x >> 6;  // 0..3
  const int b    = blockIdx.x;

  __shared__ int hbuf[4][2][32];  // [layer][slot][pair] packed f16x2

  // wA: wv0 -> Whh0 row, wv1-3 -> Wih[l-1] row (input matvec)
  // wB: wv0 -> Wfc  row, wv1-3 -> Whh[l-1] row (recurrent matvec)
  const float* pA;
  const float* pB;
  float bias;
  if (wv == 0) {
    pA = Whh0; pB = Wfc; bias = 0.f;
  } else {
    const int li = wv - 1;
    pA = Wih + li * 4096;
    pB = Whh + li * 4096;
    bias = bih[li * 64 + lane] + bhh[li * 64 + lane];
  }
  h2 wA[32], wB[32];
#pragma unroll
  for (int k = 0; k < 32; ++k)
    wA[k] = pk2(pA[lane * 64 + 2 * k], pA[lane * 64 + 2 * k + 1]);
#pragma unroll
  for (int k = 0; k < 32; ++k)
    wB[k] = pk2(pB[lane * 64 + 2 * k], pB[lane * 64 + 2 * k + 1]);
  const float fb = (wv == 0) ? bfc[lane] : 0.f;

  const long rowbase = (long)b * T_STEPS;
  const unsigned int* pp = pre0h + rowbase * 32 + (lane >> 1);  // t=0
  float* op = out + rowbase * 64 + lane;                        // t=0

  float h  = 0.f;  // own layer state h_{t-1}[lane]
  int   hp = 0;    // packed f16 pairs of h (pair k at lane 2k); f16(0)==0

  unsigned int pcur = 0;
  if (wv == 0) pcur = pp[0];  // prefetch pre0 for t=0

  for (int s = 0; s < T_STEPS + 4; ++s) {
    if (wv == 0) {
      // ---- FC stage: y_t4 = Wfc h3_t4 + bfc, t4 = s-4 ----
      if (s >= 4) {
        int ip = hbuf[3][(s - 1) & 1][lane & 31];
        float a0 = fb, a1 = 0.f;
#pragma unroll
        for (int k = 0; k < 32; k += 2) {
          a0 = fdot2f(bcast_pair(ip, k),     wB[k],     a0);
          a1 = fdot2f(bcast_pair(ip, k + 1), wB[k + 1], a1);
        }
        op[0] = a0 + a1;
        op += 64;
      }
      // ---- layer 0 recurrence at t = s ----
      if (s < T_STEPS) {
        h2 ph   = __builtin_bit_cast(h2, pcur);
        float p = (lane & 1) ? (float)ph.y : (float)ph.x;
        pp += 32;
        if (s + 1 < T_STEPS) pcur = pp[0];  // prefetch next step
        float a0 = p, a1 = 0.f;
#pragma unroll
        for (int k = 0; k < 32; k += 2) {
          a0 = fdot2f(bcast_pair(hp, 2 * k),     wA[k],     a0);
          a1 = fdot2f(bcast_pair(hp, 2 * k + 2), wA[k + 1], a1);
        }
        h  = fast_tanh(a0 + a1);
        hp = pack_own(h, lane);
        if (!(lane & 1)) hbuf[0][s & 1][lane >> 1] = hp;
      }
    } else {
      // ---- layer wv recurrence at t = s - wv ----
      const int t = s - wv;
      if (t >= 0 && t < T_STEPS) {
        int ip = hbuf[wv - 1][(s - 1) & 1][lane & 31];
        float a0 = bias, a1 = 0.f, a2 = 0.f, a3 = 0.f;
#pragma unroll
        for (int k = 0; k < 32; k += 2) {
          a0 = fdot2f(bcast_pair(ip, k),         wA[k],     a0);  // input
          a1 = fdot2f(bcast_pair(ip, k + 1),     wA[k + 1], a1);
          a2 = fdot2f(bcast_pair(hp, 2 * k),     wB[k],     a2);  // recur
          a3 = fdot2f(bcast_pair(hp, 2 * k + 2), wB[k + 1], a3);
        }
        h  = fast_tanh((a0 + a1) + (a2 + a3));
        hp = pack_own(h, lane);
        if (!(lane & 1)) hbuf[wv][s & 1][lane >> 1] = hp;
      }
    }
    __syncthreads();  // uniform: every thread, every step
  }
}

// ---------------------------------------------------------------------------
extern "C" void kernel_launch(void* const* d_in, const int* in_sizes, int n_in,
                              void* d_out, int out_size, void* d_ws,
                              size_t ws_size, hipStream_t stream) {
  const float* x    = (const float*)d_in[0];
  const float* Wih0 = (const float*)d_in[1];
  const float* Whh0 = (const float*)d_in[2];
  const float* bih0 = (const float*)d_in[3];
  const float* bhh0 = (const float*)d_in[4];
  const float* Wih  = (const float*)d_in[5];
  const float* Whh  = (const float*)d_in[6];
  const float* bih  = (const float*)d_in[7];
  const float* bhh  = (const float*)d_in[8];
  const float* Wfc  = (const float*)d_in[9];
  const float* bfc  = (const float*)d_in[10];
  float* out = (float*)d_out;

  const int B = in_sizes[0] / (T_STEPS * 52);  // 512
  const int R = B * T_STEPS;                   // rows of x / pre0

  unsigned int* pre0h = (unsigned int*)d_ws;   // R*32 uints = 64 MiB

  pre0_kernel<<<2048, 256, 0, stream>>>(x, Wih0, bih0, bhh0, pre0h, R);
  rnn_pipe<<<B, 256, 0, stream>>>(pre0h, Whh0, Wih, Whh, bih, bhh, Wfc, bfc,
                                  out);
}

// Round 3
// 866.137 us; speedup vs baseline: 1.1374x; 1.1374x over previous
//
#include <hip/hip_runtime.h>

// ---------------------------------------------------------------------------
// RNN_83313775608289: 4-layer tanh RNN (H=64) + FC, B=512, T=1024, D_in=52.
//   kernel 1 (pre0_kernel): pre0 = x @ Wih0^T + (bih0+bhh0) -> f16 [R][64]
//                           in d_ws (64 MiB). LDS-staged coalesced loads.
//   kernel 2 (rnn_pipe):    one block (8 waves, 512 thr) per batch row.
//     wave 0: h0[t] = tanh(pre0[t] + Whh0 h0[t-1])            t = s
//     wave 1: P1[t] = Wih1 h0[t]                              t = s-1
//     wave 2: h1[t] = tanh(P1[t] + Whh1 h1[t-1] + b1)         t = s-2
//     wave 3: P2[t] = Wih2 h1[t]                              t = s-3
//     wave 4: h2[t] = tanh(P2[t] + Whh2 h2[t-1] + b2)         t = s-4
//     wave 5: P3[t] = Wih3 h2[t]                              t = s-5
//     wave 6: h3[t] = tanh(P3[t] + Whh3 h3[t-1] + b3)         t = s-6
//     wave 7: out[t] = Wfc h3[t] + bfc                        t = s-7
//   h handoff via LDS f16 rows (uniform ds_read_b128 broadcast -> v_dot2),
//   P handoff via LDS f32 per-lane. One barrier per step. 32 weight pairs
//   per wave (~60 VGPRs) so weights stay in arch VGPRs.
// ---------------------------------------------------------------------------

typedef __fp16 h2 __attribute__((ext_vector_type(2)));

__device__ __forceinline__ h2 pk2(float a, float b) {
#if __has_builtin(__builtin_amdgcn_cvt_pkrtz)
  return __builtin_amdgcn_cvt_pkrtz(a, b);
#else
  h2 r; r.x = (__fp16)a; r.y = (__fp16)b; return r;
#endif
}

__device__ __forceinline__ float fdot2f(h2 a, h2 b, float c) {
#if __has_builtin(__builtin_amdgcn_fdot2)
  return __builtin_amdgcn_fdot2(a, b, c, false);
#else
  return c + (float)a.x * (float)b.x + (float)a.y * (float)b.y;
#endif
}

__device__ __forceinline__ h2 bc(unsigned int u) {
  return __builtin_bit_cast(h2, u);
}

__device__ __forceinline__ float fast_tanh(float x) {
  float e = __expf(2.0f * x);          // overflow -> +inf -> result 1.0 (ok)
#if __has_builtin(__builtin_amdgcn_rcpf)
  return 1.0f - 2.0f * __builtin_amdgcn_rcpf(e + 1.0f);
#else
  return 1.0f - 2.0f / (e + 1.0f);
#endif
}

#define T_STEPS 1024

// ---------------------------------------------------------------------------
// Kernel 1: block = 256 thr handles 64 rows of x. Stage 64x52 f32 in LDS via
// coalesced float4, then each wave computes 16 rows: uniform float4 LDS reads
// (x pairs broadcast) x per-lane f16 weight pairs -> dot2.
// ---------------------------------------------------------------------------
__global__ __launch_bounds__(256) void pre0_kernel(
    const float* __restrict__ x, const float* __restrict__ Wih0,
    const float* __restrict__ bih0, const float* __restrict__ bhh0,
    __fp16* __restrict__ pre0h) {
  __shared__ float xs[64 * 52];  // 13312 B
  const int tid  = threadIdx.x;
  const int lane = tid & 63;
  const int wv   = tid >> 6;

  // coalesced tile copy: 64 rows * 52 f32 = 832 float4
  const float4* g4 = (const float4*)(x + (long)blockIdx.x * 64 * 52);
  float4* s4 = (float4*)xs;
#pragma unroll
  for (int i = 0; i < 4; ++i) {
    int idx = tid + i * 256;
    if (idx < 832) s4[idx] = g4[idx];
  }

  // lane j holds Wih0 row j as 26 f16 pairs
  h2 w[26];
  const float2* w2 = (const float2*)(Wih0 + lane * 52);
#pragma unroll
  for (int k = 0; k < 26; ++k) {
    float2 v = w2[k];
    w[k] = pk2(v.x, v.y);
  }
  const float bias = bih0[lane] + bhh0[lane];
  __syncthreads();

  const long obase = (long)blockIdx.x * 64;
#pragma unroll 1
  for (int r = wv * 16; r < wv * 16 + 16; ++r) {
    const float4* xr = (const float4*)(xs + r * 52);  // uniform per wave
    float a0 = bias, a1 = 0.f;
#pragma unroll
    for (int q = 0; q < 13; ++q) {
      float4 v = xr[q];
      a0 = fdot2f(pk2(v.x, v.y), w[2 * q],     a0);
      a1 = fdot2f(pk2(v.z, v.w), w[2 * q + 1], a1);
    }
    pre0h[(obase + r) * 64 + lane] = (__fp16)(a0 + a1);
  }
}

// ---------------------------------------------------------------------------
// Kernel 2: 8-wave pipelined scan. See header comment for roles/skew.
// ---------------------------------------------------------------------------
__global__ __launch_bounds__(512, 4) void rnn_pipe(
    const __fp16* __restrict__ pre0h, const float* __restrict__ Whh0,
    const float* __restrict__ Wih, const float* __restrict__ Whh,
    const float* __restrict__ bih, const float* __restrict__ bhh,
    const float* __restrict__ Wfc, const float* __restrict__ bfc,
    float* __restrict__ out) {
  const int tid  = threadIdx.x;
  const int lane = tid & 63;
  const int wv   = tid >> 6;  // 0..7
  const int b    = blockIdx.x;

  __shared__ __attribute__((aligned(16))) __fp16 hbuf[4][2][64];  // 1 KiB
  __shared__ float Pbuf[3][2][64];                                // 1.5 KiB

  // zero-init h state (both slots represent h[t=-1] = 0 until overwritten)
  if (tid < 256) ((float*)hbuf)[tid] = 0.f;

  // role/weights per wave
  // even wv (0,2,4,6): recurrent+tanh for layer L=wv/2 (weights Whh_L)
  // odd  wv (1,3,5):   input GEMV for layer L=(wv+1)/2 (weights Wih_L)
  // wv 7:              FC (weights Wfc)
  const float* W;
  float bias = 0.f;
  int role, L;
  if (wv == 7) {
    role = 2; L = 3; W = Wfc; bias = bfc[lane];
  } else if ((wv & 1) == 0) {
    role = 0; L = wv >> 1;
    W = (L == 0) ? Whh0 : (Whh + (L - 1) * 4096);
    if (L > 0) bias = bih[(L - 1) * 64 + lane] + bhh[(L - 1) * 64 + lane];
  } else {
    role = 1; L = (wv + 1) >> 1;
    W = Wih + (L - 1) * 4096;
  }

  h2 w[32];
  const float2* wsrc = (const float2*)(W + lane * 64);
#pragma unroll
  for (int k = 0; k < 32; ++k) {
    float2 v = wsrc[k];
    w[k] = pk2(v.x, v.y);
  }

  const long rowbase = (long)b * T_STEPS;
  const __fp16* pp = pre0h + rowbase * 64 + lane;
  float* op = out + rowbase * 64 + lane;

  float pcur = (wv == 0) ? (float)pp[0] : 0.f;  // prefetch p[t=0]

  __syncthreads();

  for (int s = 0; s < T_STEPS + 7; ++s) {
    const int t  = s - wv;
    const int rd = (s - 1) & 1;
    const int wr = s & 1;
    if (t >= 0 && t < T_STEPS) {
      if (role == 0) {
        // h_L[t] = tanh( part + Whh_L * h_L[t-1] + bias )
        const uint4* hb = (const uint4*)hbuf[L][rd];  // uniform broadcast
        float a0 = bias, a1 = 0.f, a2 = 0.f, a3 = 0.f;
#pragma unroll
        for (int q = 0; q < 8; ++q) {
          uint4 u = hb[q];
          a0 = fdot2f(bc(u.x), w[4 * q + 0], a0);
          a1 = fdot2f(bc(u.y), w[4 * q + 1], a1);
          a2 = fdot2f(bc(u.z), w[4 * q + 2], a2);
          a3 = fdot2f(bc(u.w), w[4 * q + 3], a3);
        }
        float part;
        if (L == 0) {
          part = pcur;
          pp += 64;
          if (t + 1 < T_STEPS) pcur = (float)pp[0];  // prefetch next p
        } else {
          part = Pbuf[L - 1][rd][lane];
        }
        float h = fast_tanh(((a0 + a1) + (a2 + a3)) + part);
        hbuf[L][wr][lane] = (__fp16)h;
      } else if (role == 1) {
        // P_L[t] = Wih_L * h_{L-1}[t]
        const uint4* hb = (const uint4*)hbuf[L - 1][rd];
        float a0 = 0.f, a1 = 0.f, a2 = 0.f, a3 = 0.f;
#pragma unroll
        for (int q = 0; q < 8; ++q) {
          uint4 u = hb[q];
          a0 = fdot2f(bc(u.x), w[4 * q + 0], a0);
          a1 = fdot2f(bc(u.y), w[4 * q + 1], a1);
          a2 = fdot2f(bc(u.z), w[4 * q + 2], a2);
          a3 = fdot2f(bc(u.w), w[4 * q + 3], a3);
        }
        Pbuf[L - 1][wr][lane] = (a0 + a1) + (a2 + a3);
      } else {
        // out[t] = Wfc * h3[t] + bfc
        const uint4* hb = (const uint4*)hbuf[3][rd];
        float a0 = bias, a1 = 0.f, a2 = 0.f, a3 = 0.f;
#pragma unroll
        for (int q = 0; q < 8; ++q) {
          uint4 u = hb[q];
          a0 = fdot2f(bc(u.x), w[4 * q + 0], a0);
          a1 = fdot2f(bc(u.y), w[4 * q + 1], a1);
          a2 = fdot2f(bc(u.z), w[4 * q + 2], a2);
          a3 = fdot2f(bc(u.w), w[4 * q + 3], a3);
        }
        op[0] = (a0 + a1) + (a2 + a3);
        op += 64;
      }
    }
    __syncthreads();  // uniform: every thread, every step
  }
}

// ---------------------------------------------------------------------------
extern "C" void kernel_launch(void* const* d_in, const int* in_sizes, int n_in,
                              void* d_out, int out_size, void* d_ws,
                              size_t ws_size, hipStream_t stream) {
  const float* x    = (const float*)d_in[0];
  const float* Wih0 = (const float*)d_in[1];
  const float* Whh0 = (const float*)d_in[2];
  const float* bih0 = (const float*)d_in[3];
  const float* bhh0 = (const float*)d_in[4];
  const float* Wih  = (const float*)d_in[5];
  const float* Whh  = (const float*)d_in[6];
  const float* bih  = (const float*)d_in[7];
  const float* bhh  = (const float*)d_in[8];
  const float* Wfc  = (const float*)d_in[9];
  const float* bfc  = (const float*)d_in[10];
  float* out = (float*)d_out;

  const int B = in_sizes[0] / (T_STEPS * 52);  // 512
  const int R = B * T_STEPS;

  __fp16* pre0h = (__fp16*)d_ws;  // R*64 f16 = 64 MiB

  pre0_kernel<<<R / 64, 256, 0, stream>>>(x, Wih0, bih0, bhh0, pre0h);
  rnn_pipe<<<B, 512, 0, stream>>>(pre0h, Whh0, Wih, Whh, bih, bhh, Wfc, bfc,
                                  out);
}